// Round 1
// baseline (71.946 us; speedup 1.0000x reference)
//
#include <hip/hip_runtime.h>

// Problem constants (from reference): B=16384, L=200, V=1000000, D=20
static constexpr int B = 16384;
static constexpr int L = 200;
static constexpr int D = 20;

// One 64-lane wave per batch row; 4 waves (256 threads) per block.
__global__ __launch_bounds__(256) void wd_pool_kernel(
    const int* __restrict__ ids,    // [B, L] int32
    const float* __restrict__ emb,  // [V, D] f32, row 0 == zeros
    float* __restrict__ out)        // [B, D] f32
{
    const int lane = threadIdx.x & 63;
    const int row  = (blockIdx.x << 2) + (threadIdx.x >> 6);

    const int* __restrict__ rid = ids + (size_t)row * L;

    float a[D];
#pragma unroll
    for (int i = 0; i < D; ++i) a[i] = 0.0f;
    float cntf = 0.0f;

    // Lane-strided token loop: lane l handles tokens l, l+64, l+128, l+192.
    for (int t = lane; t < L; t += 64) {
        const int id = rid[t];
        if (id != 0) {  // row 0 is all-zero -> never kept; skip the gather
            const float4* __restrict__ r =
                (const float4*)(emb + (size_t)id * D);  // 80B, 16B-aligned
            float4 v[5];
#pragma unroll
            for (int q = 0; q < 5; ++q) v[q] = r[q];

            // keep = (sum over 20 dims != 0)  -- matches reference semantics
            float s = 0.0f;
#pragma unroll
            for (int q = 0; q < 5; ++q) s += (v[q].x + v[q].y) + (v[q].z + v[q].w);

            const float k = (s != 0.0f) ? 1.0f : 0.0f;
#pragma unroll
            for (int q = 0; q < 5; ++q) {
                a[4 * q + 0] += v[q].x * k;
                a[4 * q + 1] += v[q].y * k;
                a[4 * q + 2] += v[q].z * k;
                a[4 * q + 3] += v[q].w * k;
            }
            cntf += k;
        }
    }

    // Butterfly reduction across the 64-lane wave (21 values x 6 steps).
#pragma unroll
    for (int off = 32; off; off >>= 1) {
#pragma unroll
        for (int i = 0; i < D; ++i) a[i] += __shfl_xor(a[i], off, 64);
        cntf += __shfl_xor(cntf, off, 64);
    }

    if (lane == 0) {
        // cnt==0 -> acc==0 -> 0/1 == 0, which matches the zeros fallback.
        const float inv = 1.0f / fmaxf(cntf, 1.0f);
        float4* __restrict__ o = (float4*)(out + (size_t)row * D);
#pragma unroll
        for (int q = 0; q < 5; ++q) {
            float4 w;
            w.x = a[4 * q + 0] * inv;
            w.y = a[4 * q + 1] * inv;
            w.z = a[4 * q + 2] * inv;
            w.w = a[4 * q + 3] * inv;
            o[q] = w;
        }
    }
}

extern "C" void kernel_launch(void* const* d_in, const int* in_sizes, int n_in,
                              void* d_out, int out_size, void* d_ws, size_t ws_size,
                              hipStream_t stream) {
    const int*   ids = (const int*)d_in[0];
    const float* emb = (const float*)d_in[1];
    float*       out = (float*)d_out;

    dim3 grid(B / 4);   // 4 rows (waves) per 256-thread block
    dim3 block(256);
    hipLaunchKernelGGL(wd_pool_kernel, grid, block, 0, stream, ids, emb, out);
}

// Round 2
// 69.575 us; speedup vs baseline: 1.0341x; 1.0341x over previous
//
#include <hip/hip_runtime.h>

// Problem constants (from reference): B=16384, L=200, V=1000000, D=20
static constexpr int B = 16384;
static constexpr int L = 200;
static constexpr int D = 20;
static constexpr int TPL = (L + 63) / 64;  // max tokens per lane = 4

// One 64-lane wave per batch row; 4 waves (256 threads) per block.
__global__ __launch_bounds__(256) void wd_pool_kernel(
    const int* __restrict__ ids,    // [B, L] int32
    const float* __restrict__ emb,  // [V, D] f32, row 0 == zeros
    float* __restrict__ out)        // [B, D] f32
{
    const int lane = threadIdx.x & 63;
    const int row  = (blockIdx.x << 2) + (threadIdx.x >> 6);

    const int* __restrict__ rid = ids + (size_t)row * L;

    // Phase 1: all token ids for this lane (coalesced; one wait).
    int id[TPL];
#pragma unroll
    for (int j = 0; j < TPL; ++j) {
        const int t = lane + 64 * j;
        id[j] = (t < L) ? rid[t] : 0;  // OOB -> row 0 (all-zero, L1-hot)
    }

    // Phase 2: issue ALL gathers back-to-back (max MLP). Row 0 reads are
    // unconditional on purpose: branch-free issue; the two cache lines of
    // row 0 stay L1-resident, so padding lanes cost ~nothing.
    float4 v[TPL][5];
#pragma unroll
    for (int j = 0; j < TPL; ++j) {
        const float4* __restrict__ r =
            (const float4*)(emb + (size_t)id[j] * D);  // 80 B, 16 B-aligned
#pragma unroll
        for (int q = 0; q < 5; ++q) v[j][q] = r[q];
    }

    // Phase 3: keep-filter + accumulate (matches reference: keep iff sum != 0).
    float a[D];
#pragma unroll
    for (int i = 0; i < D; ++i) a[i] = 0.0f;
    float cntf = 0.0f;

#pragma unroll
    for (int j = 0; j < TPL; ++j) {
        float s = 0.0f;
#pragma unroll
        for (int q = 0; q < 5; ++q)
            s += (v[j][q].x + v[j][q].y) + (v[j][q].z + v[j][q].w);
        const float k = (s != 0.0f) ? 1.0f : 0.0f;
#pragma unroll
        for (int q = 0; q < 5; ++q) {
            a[4 * q + 0] += v[j][q].x * k;
            a[4 * q + 1] += v[j][q].y * k;
            a[4 * q + 2] += v[j][q].z * k;
            a[4 * q + 3] += v[j][q].w * k;
        }
        cntf += k;
    }

    // Phase 4: butterfly reduction across the 64-lane wave.
#pragma unroll
    for (int off = 32; off; off >>= 1) {
#pragma unroll
        for (int i = 0; i < D; ++i) a[i] += __shfl_xor(a[i], off, 64);
        cntf += __shfl_xor(cntf, off, 64);
    }

    if (lane == 0) {
        // cnt==0 -> acc==0 -> 0/1 == 0 == reference's zeros fallback.
        const float inv = 1.0f / fmaxf(cntf, 1.0f);
        float4* __restrict__ o = (float4*)(out + (size_t)row * D);
#pragma unroll
        for (int q = 0; q < 5; ++q) {
            float4 w;
            w.x = a[4 * q + 0] * inv;
            w.y = a[4 * q + 1] * inv;
            w.z = a[4 * q + 2] * inv;
            w.w = a[4 * q + 3] * inv;
            o[q] = w;
        }
    }
}

extern "C" void kernel_launch(void* const* d_in, const int* in_sizes, int n_in,
                              void* d_out, int out_size, void* d_ws, size_t ws_size,
                              hipStream_t stream) {
    const int*   ids = (const int*)d_in[0];
    const float* emb = (const float*)d_in[1];
    float*       out = (float*)d_out;

    dim3 grid(B / 4);   // 4 rows (waves) per 256-thread block
    dim3 block(256);
    hipLaunchKernelGGL(wd_pool_kernel, grid, block, 0, stream, ids, emb, out);
}

// Round 3
// 68.082 us; speedup vs baseline: 1.0568x; 1.0219x over previous
//
#include <hip/hip_runtime.h>

// Problem constants (from reference): B=16384, L=200, V=1000000, D=20
static constexpr int B = 16384;
static constexpr int L = 200;
static constexpr int D = 20;
static constexpr int TPL = (L + 63) / 64;  // max tokens per lane = 4

// One 64-lane wave per batch row; 4 waves (256 threads) per block.
__global__ __launch_bounds__(256) void wd_pool_kernel(
    const int* __restrict__ ids,    // [B, L] int32
    const float* __restrict__ emb,  // [V, D] f32, row 0 == zeros
    float* __restrict__ out)        // [B, D] f32
{
    const int lane = threadIdx.x & 63;
    const int row  = (blockIdx.x << 2) + (threadIdx.x >> 6);

    const int* __restrict__ rid = ids + (size_t)row * L;

    // Phase 1: all token ids for this lane (coalesced; one wait).
    int id[TPL];
#pragma unroll
    for (int j = 0; j < TPL; ++j) {
        const int t = lane + 64 * j;
        id[j] = (t < L) ? rid[t] : 0;  // OOB -> row 0 (all-zero, L1-hot)
    }

    // Phase 2: issue ALL 20 gather float4 loads back-to-back, then a hard
    // scheduling fence. Without the fence the MIR scheduler sinks each load
    // next to its consumer (R2 showed VGPR=36 => ~5 in flight); the fence
    // forces all 20 destinations live => ~20 outstanding loads per wave.
    float4 v[TPL][5];
#pragma unroll
    for (int j = 0; j < TPL; ++j) {
        const float4* __restrict__ r =
            (const float4*)(emb + (size_t)id[j] * D);  // 80 B, 16 B-aligned
#pragma unroll
        for (int q = 0; q < 5; ++q) v[j][q] = r[q];
    }
    __builtin_amdgcn_sched_barrier(0);  // nothing crosses: loads stay hoisted

    // Phase 3: keep-filter + accumulate (matches reference: keep iff sum != 0).
    float a[D];
#pragma unroll
    for (int i = 0; i < D; ++i) a[i] = 0.0f;
    float cntf = 0.0f;

#pragma unroll
    for (int j = 0; j < TPL; ++j) {
        float s = 0.0f;
#pragma unroll
        for (int q = 0; q < 5; ++q)
            s += (v[j][q].x + v[j][q].y) + (v[j][q].z + v[j][q].w);
        const float k = (s != 0.0f) ? 1.0f : 0.0f;
#pragma unroll
        for (int q = 0; q < 5; ++q) {
            a[4 * q + 0] += v[j][q].x * k;
            a[4 * q + 1] += v[j][q].y * k;
            a[4 * q + 2] += v[j][q].z * k;
            a[4 * q + 3] += v[j][q].w * k;
        }
        cntf += k;
    }

    // Phase 4: butterfly reduction across the 64-lane wave.
#pragma unroll
    for (int off = 32; off; off >>= 1) {
#pragma unroll
        for (int i = 0; i < D; ++i) a[i] += __shfl_xor(a[i], off, 64);
        cntf += __shfl_xor(cntf, off, 64);
    }

    if (lane == 0) {
        // cnt==0 -> acc==0 -> 0/1 == 0 == reference's zeros fallback.
        const float inv = 1.0f / fmaxf(cntf, 1.0f);
        float4* __restrict__ o = (float4*)(out + (size_t)row * D);
#pragma unroll
        for (int q = 0; q < 5; ++q) {
            float4 w;
            w.x = a[4 * q + 0] * inv;
            w.y = a[4 * q + 1] * inv;
            w.z = a[4 * q + 2] * inv;
            w.w = a[4 * q + 3] * inv;
            o[q] = w;
        }
    }
}

extern "C" void kernel_launch(void* const* d_in, const int* in_sizes, int n_in,
                              void* d_out, int out_size, void* d_ws, size_t ws_size,
                              hipStream_t stream) {
    const int*   ids = (const int*)d_in[0];
    const float* emb = (const float*)d_in[1];
    float*       out = (float*)d_out;

    dim3 grid(B / 4);   // 4 rows (waves) per 256-thread block
    dim3 block(256);
    hipLaunchKernelGGL(wd_pool_kernel, grid, block, 0, stream, ids, emb, out);
}